// Round 15
// baseline (336.868 us; speedup 1.0000x reference)
//
#include <hip/hip_runtime.h>
#include <hip/hip_bf16.h>
#include <cstdint>

#define N_TOK 32768
#define CTX   256
#define DIM   1024
#define NH    16
#define HD    64

typedef __attribute__((ext_vector_type(8))) short short8;
typedef __attribute__((ext_vector_type(4))) float f32x4;
typedef __attribute__((ext_vector_type(4))) unsigned short ushort4v;

#define AS1 __attribute__((address_space(1)))
#define AS3 __attribute__((address_space(3)))

__device__ inline unsigned short f2bf(float f) {
  union { float f; unsigned int u; } v; v.f = f;
  unsigned int r = v.u + 0x7fffu + ((v.u >> 16) & 1u);
  return (unsigned short)(r >> 16);
}

__device__ inline unsigned int cvtpk_bf16(float a, float b) {
  unsigned int r;
  asm("v_cvt_pk_bf16_f32 %0, %1, %2" : "=v"(r) : "v"(a), "v"(b));
  return r;  // low16 = bf16(a), high16 = bf16(b)
}

// ---------------- f32 -> bf16 convert (vectorized, grid-stride) ----------------
__global__ void cvt_kernel(const float* __restrict__ in, unsigned short* __restrict__ out, int n4) {
  int i = blockIdx.x * blockDim.x + threadIdx.x;
  int stride = gridDim.x * blockDim.x;
  for (int j = i; j < n4; j += stride) {
    float4 v = reinterpret_cast<const float4*>(in)[j];
    ushort4v o;
    o.x = f2bf(v.x); o.y = f2bf(v.y); o.z = f2bf(v.z); o.w = f2bf(v.w);
    reinterpret_cast<ushort4v*>(out)[j] = o;
  }
}

// batched small converts
__global__ void cvt_multi(const float* __restrict__ s0, const float* __restrict__ s1,
                          const float* __restrict__ s2, const float* __restrict__ s3,
                          const float* __restrict__ s4,
                          unsigned short* __restrict__ d0, unsigned short* __restrict__ d1,
                          unsigned short* __restrict__ d2, unsigned short* __restrict__ d3,
                          unsigned short* __restrict__ d4) {
  const float* s; unsigned short* d; int n4;
  switch (blockIdx.y) {
    case 0: s = s0; d = d0; n4 = (DIM * DIM) / 4; break;
    case 1: s = s1; d = d1; n4 = (DIM * DIM) / 4; break;
    case 2: s = s2; d = d2; n4 = (DIM * DIM) / 4; break;
    case 3: s = s3; d = d3; n4 = (DIM * DIM) / 4; break;
    default: s = s4; d = d4; n4 = (CTX * DIM) / 4; break;
  }
  int i = blockIdx.x * blockDim.x + threadIdx.x;
  int stride = gridDim.x * blockDim.x;
  for (int j = i; j < n4; j += stride) {
    float4 v = reinterpret_cast<const float4*>(s)[j];
    ushort4v o;
    o.x = f2bf(v.x); o.y = f2bf(v.y); o.z = f2bf(v.z); o.w = f2bf(v.w);
    reinterpret_cast<ushort4v*>(d)[j] = o;
  }
}

// ---------------- small bf16 GEMM (m97 structure), K/V projections ----------------
// OUTMODE 3 = V fragment layout (PV B-operand); OUTMODE 4 = K fragment layout
// (QK^T A-operand): Kg[h][cf][kk][lane][8], lane=(c&15)+16*((d>>3)&3), j=d&7.
template <int OUTMODE>
__global__ __launch_bounds__(256) void gemm_bt(const unsigned short* __restrict__ A,
                                               const unsigned short* __restrict__ B,
                                               void* __restrict__ Cout,
                                               int M, int N, int K) {
  __shared__ unsigned short As[128 * 32];
  __shared__ unsigned short Bs[128 * 32];
  const int tid  = threadIdx.x;
  const int lane = tid & 63;
  const int wid  = tid >> 6;
  const int wr = wid >> 1, wc = wid & 1;
  const int bx = blockIdx.x, by = blockIdx.y;
  const long arow0 = (long)by * 128;
  const long brow0 = (long)bx * 128;
  const int sr = tid >> 2;
  const int sc = (tid & 3) * 8;

  f32x4 acc[4][4];
#pragma unroll
  for (int i = 0; i < 4; ++i)
#pragma unroll
    for (int j = 0; j < 4; ++j) acc[i][j] = (f32x4){0.f, 0.f, 0.f, 0.f};

  const int ar = wr * 64 + (lane & 15);
  const int br = wc * 64 + (lane & 15);
  const int kc = (lane >> 4) * 8;

  for (int k0 = 0; k0 < K; k0 += 32) {
#pragma unroll
    for (int pass = 0; pass < 2; ++pass) {
      int r = pass * 64 + sr;
      const unsigned short* ga = &A[(arow0 + r) * K + k0 + sc];
      const unsigned short* gb = &B[(brow0 + r) * K + k0 + sc];
      __builtin_amdgcn_global_load_lds((const AS1 unsigned int*)ga,
                                       (AS3 unsigned int*)&As[(size_t)tid * 8 + pass * 2048], 16, 0, 0);
      __builtin_amdgcn_global_load_lds((const AS1 unsigned int*)gb,
                                       (AS3 unsigned int*)&Bs[(size_t)tid * 8 + pass * 2048], 16, 0, 0);
    }
    __syncthreads();
    short8 a[4], b[4];
#pragma unroll
    for (int mf = 0; mf < 4; ++mf) a[mf] = *(const short8*)&As[(ar + mf * 16) * 32 + kc];
#pragma unroll
    for (int nf = 0; nf < 4; ++nf) b[nf] = *(const short8*)&Bs[(br + nf * 16) * 32 + kc];
#pragma unroll
    for (int mf = 0; mf < 4; ++mf)
#pragma unroll
      for (int nf = 0; nf < 4; ++nf)
        acc[mf][nf] = __builtin_amdgcn_mfma_f32_16x16x32_bf16(a[mf], b[nf], acc[mf][nf], 0, 0, 0);
    __syncthreads();
  }

  const long row0 = (long)by * 128 + wr * 64 + ((lane >> 4) << 2);
  const long col0 = (long)bx * 128 + wc * 64 + (lane & 15);
  unsigned short* C = (unsigned short*)Cout;
#pragma unroll
  for (int mf = 0; mf < 4; ++mf)
#pragma unroll
    for (int q = 0; q < 4; ++q) {
      const int c = (int)(row0 + mf * 16 + q);     // context idx 0..255
#pragma unroll
      for (int nf = 0; nf < 4; ++nf) {
        const int dcol = (int)(col0 + nf * 16);    // 0..1023
        size_t off;
        if (OUTMODE == 3) {
          off = (size_t)(dcol >> 6) * 16384 +
                (size_t)((c >> 5) * 4 + ((dcol >> 4) & 3)) * 512 +
                (size_t)(((c >> 3) & 3) * 16 + (dcol & 15)) * 8 +
                (size_t)(c & 7);
        } else {  // OUTMODE 4: K A-fragment layout
          const int d = dcol & 63;
          off = (size_t)(dcol >> 6) * 16384 +      // head
                (size_t)(c >> 4) * 1024 +          // cf
                (size_t)(d >> 5) * 512 +           // kk
                (size_t)((c & 15) + 16 * ((d >> 3) & 3)) * 8 +
                (size_t)(d & 7);
        }
        C[off] = f2bf(acc[mf][nf][q]);
      }
    }
}

// ---------------- fused Q-projection + attention ----------------
// Main loop: r9 4-phase 256x256 bf16 GEMM (proven 78us). Epilogue: each wave owns
// head h = bx*4+wc for its 128 rows (its acc quadrant IS complete Q for that head).
// Per 16-row sub-tile (wave-private, NO barriers): acc->LDS (swizzled), aq frags,
// QK^T with K from Kg (A-fragment global layout, L2-hot coalesced), softmax
// (raw exp2, no max-subtract), P->LDS, PV with Vg, normalized AO store.
__global__ __launch_bounds__(512, 2) void gemm256_qattn(const unsigned short* __restrict__ A,
                                                        const unsigned short* __restrict__ B,
                                                        const unsigned short* __restrict__ Kg,
                                                        const unsigned short* __restrict__ Vg,
                                                        unsigned short* __restrict__ AO,
                                                        int M, int N, int K, int nbx) {
  __shared__ unsigned short As[2][256 * 64];
  __shared__ unsigned short Bs[2][256 * 64];
  const int tid  = threadIdx.x;
  const int lane = tid & 63;
  const int wid  = tid >> 6;
  const int wr = wid >> 2;
  const int wc = wid & 3;
  const int lo = lane & 15, hi4 = lane >> 4, lo7 = lane & 7;

  const int nwg = gridDim.x;
  const int cpx = nwg >> 3;
  int flat = blockIdx.x;
  flat = (flat & 7) * cpx + (flat >> 3);
  const int bx = flat % nbx;
  const int by = flat / nbx;

  const long arow0 = (long)by * 256;
  const long brow0 = (long)bx * 256;
  const int nt = K >> 6;
  const int nj = nt >> 1;

  auto stageA = [&](int buf, int t) {
#pragma unroll
    for (int li = 0; li < 4; ++li) {
      int gi = li * 512 + tid;
      int row = gi >> 3;
      int cg = (gi & 7) ^ (row & 7);
      __builtin_amdgcn_global_load_lds(
          (const AS1 unsigned int*)&A[(arow0 + row) * K + (t << 6) + cg * 8],
          (AS3 unsigned int*)&As[buf][gi * 8], 16, 0, 0);
    }
  };
  auto stageB = [&](int buf, int t) {
#pragma unroll
    for (int li = 0; li < 4; ++li) {
      int gi = li * 512 + tid;
      int row = gi >> 3;
      int cg = (gi & 7) ^ (row & 7);
      __builtin_amdgcn_global_load_lds(
          (const AS1 unsigned int*)&B[(brow0 + row) * K + (t << 6) + cg * 8],
          (AS3 unsigned int*)&Bs[buf][gi * 8], 16, 0, 0);
    }
  };

  f32x4 acc[8][4];
#pragma unroll
  for (int i = 0; i < 8; ++i)
#pragma unroll
    for (int j = 0; j < 4; ++j) acc[i][j] = (f32x4){0.f, 0.f, 0.f, 0.f};

  stageA(0, 0);
  stageB(0, 0);
  stageB(1, 1);

  for (int j = 0; j < nj; ++j) {
    const int p = 2 * j;
    const bool more = (j + 1 < nj);
    short8 b[4][2];

    asm volatile("s_waitcnt vmcnt(4)" ::: "memory");
    __builtin_amdgcn_sched_barrier(0);
    __builtin_amdgcn_s_barrier();
    {
      short8 a[4][2];
#pragma unroll
      for (int nf = 0; nf < 4; ++nf)
#pragma unroll
        for (int kk = 0; kk < 2; ++kk) {
          const int row = wc * 64 + nf * 16 + lo;
          b[nf][kk] = *(const short8*)&Bs[0][row * 64 + ((kk * 4 + hi4) ^ lo7) * 8];
        }
#pragma unroll
      for (int mf = 0; mf < 4; ++mf)
#pragma unroll
        for (int kk = 0; kk < 2; ++kk) {
          const int row = wr * 128 + mf * 16 + lo;
          a[mf][kk] = *(const short8*)&As[0][row * 64 + ((kk * 4 + hi4) ^ lo7) * 8];
        }
      stageA(1, p + 1);
      __builtin_amdgcn_s_barrier();
      asm volatile("s_waitcnt lgkmcnt(0)" ::: "memory");
      __builtin_amdgcn_s_setprio(1);
#pragma unroll
      for (int kk = 0; kk < 2; ++kk)
#pragma unroll
        for (int mf = 0; mf < 4; ++mf)
#pragma unroll
          for (int nf = 0; nf < 4; ++nf)
            acc[mf][nf] = __builtin_amdgcn_mfma_f32_16x16x32_bf16(a[mf][kk], b[nf][kk], acc[mf][nf], 0, 0, 0);
      __builtin_amdgcn_s_setprio(0);
    }
    {
      short8 a[4][2];
#pragma unroll
      for (int mf = 0; mf < 4; ++mf)
#pragma unroll
        for (int kk = 0; kk < 2; ++kk) {
          const int row = wr * 128 + (mf + 4) * 16 + lo;
          a[mf][kk] = *(const short8*)&As[0][row * 64 + ((kk * 4 + hi4) ^ lo7) * 8];
        }
      if (more) stageB(0, p + 2);
      __builtin_amdgcn_s_barrier();
      asm volatile("s_waitcnt lgkmcnt(0)" ::: "memory");
      __builtin_amdgcn_s_setprio(1);
#pragma unroll
      for (int kk = 0; kk < 2; ++kk)
#pragma unroll
        for (int mf = 0; mf < 4; ++mf)
#pragma unroll
          for (int nf = 0; nf < 4; ++nf)
            acc[mf + 4][nf] = __builtin_amdgcn_mfma_f32_16x16x32_bf16(a[mf][kk], b[nf][kk], acc[mf + 4][nf], 0, 0, 0);
      __builtin_amdgcn_s_setprio(0);
    }
    if (more) asm volatile("s_waitcnt vmcnt(4)" ::: "memory");
    else      asm volatile("s_waitcnt vmcnt(0)" ::: "memory");
    __builtin_amdgcn_sched_barrier(0);
    __builtin_amdgcn_s_barrier();
    {
      short8 a[4][2];
#pragma unroll
      for (int nf = 0; nf < 4; ++nf)
#pragma unroll
        for (int kk = 0; kk < 2; ++kk) {
          const int row = wc * 64 + nf * 16 + lo;
          b[nf][kk] = *(const short8*)&Bs[1][row * 64 + ((kk * 4 + hi4) ^ lo7) * 8];
        }
#pragma unroll
      for (int mf = 0; mf < 4; ++mf)
#pragma unroll
        for (int kk = 0; kk < 2; ++kk) {
          const int row = wr * 128 + mf * 16 + lo;
          a[mf][kk] = *(const short8*)&As[1][row * 64 + ((kk * 4 + hi4) ^ lo7) * 8];
        }
      if (more) stageA(0, p + 2);
      __builtin_amdgcn_s_barrier();
      asm volatile("s_waitcnt lgkmcnt(0)" ::: "memory");
      __builtin_amdgcn_s_setprio(1);
#pragma unroll
      for (int kk = 0; kk < 2; ++kk)
#pragma unroll
        for (int mf = 0; mf < 4; ++mf)
#pragma unroll
          for (int nf = 0; nf < 4; ++nf)
            acc[mf][nf] = __builtin_amdgcn_mfma_f32_16x16x32_bf16(a[mf][kk], b[nf][kk], acc[mf][nf], 0, 0, 0);
      __builtin_amdgcn_s_setprio(0);
    }
    {
      short8 a[4][2];
#pragma unroll
      for (int mf = 0; mf < 4; ++mf)
#pragma unroll
        for (int kk = 0; kk < 2; ++kk) {
          const int row = wr * 128 + (mf + 4) * 16 + lo;
          a[mf][kk] = *(const short8*)&As[1][row * 64 + ((kk * 4 + hi4) ^ lo7) * 8];
        }
      if (more) stageB(1, p + 3);
      __builtin_amdgcn_s_barrier();
      asm volatile("s_waitcnt lgkmcnt(0)" ::: "memory");
      __builtin_amdgcn_s_setprio(1);
#pragma unroll
      for (int kk = 0; kk < 2; ++kk)
#pragma unroll
        for (int mf = 0; mf < 4; ++mf)
#pragma unroll
          for (int nf = 0; nf < 4; ++nf)
            acc[mf + 4][nf] = __builtin_amdgcn_mfma_f32_16x16x32_bf16(a[mf][kk], b[nf][kk], acc[mf + 4][nf], 0, 0, 0);
      __builtin_amdgcn_s_setprio(0);
    }
  }

  // ---- fused attention epilogue ----
  __builtin_amdgcn_s_barrier();   // reclaim As: all waves' main-loop LDS reads done
  unsigned short* W = &As[0][0] + wid * 4096;   // 8KB wave-private region
  const int h = bx * 4 + wc;                    // this wave's complete head
  const unsigned short* kgb = &Kg[(size_t)h * 16384 + (size_t)lane * 8];
  const unsigned short* vgb = &Vg[(size_t)h * 16384 + (size_t)lane * 8];
  const float cexp = 0.125f * 1.44269504088896f;  // SCALE * log2(e)
  const long rowb = (long)by * 256 + wr * 128;

#pragma unroll
  for (int st = 0; st < 8; ++st) {
    // Q sub-tile (16 rows x 64 d) -> W, granule-swizzled (slot = (col>>3) ^ (row&7))
#pragma unroll
    for (int q = 0; q < 4; ++q) {
      const int row = (hi4 << 2) + q;
#pragma unroll
      for (int nf = 0; nf < 4; ++nf) {
        const int col = nf * 16 + lo;
        W[row * 64 + (((col >> 3) ^ (row & 7)) << 3) + (col & 7)] = f2bf(acc[st][nf][q]);
      }
    }
    // Q B-fragments: lane's q-row = lo, d-slices hi4*8 and 32+hi4*8
    short8 aq0 = *(const short8*)&W[lo * 64 + ((hi4 ^ lo7) << 3)];
    short8 aq1 = *(const short8*)&W[lo * 64 + (((hi4 + 4) ^ lo7) << 3)];

    // S^T = K Q : lane owns S[q=lo][c = cf*16 + hi4*4 + qq]
    f32x4 s[16];
#pragma unroll
    for (int cf = 0; cf < 16; ++cf) {
      short8 k0 = *(const short8*)&kgb[cf * 1024];
      short8 k1 = *(const short8*)&kgb[cf * 1024 + 512];
      f32x4 z = (f32x4){0.f, 0.f, 0.f, 0.f};
      z = __builtin_amdgcn_mfma_f32_16x16x32_bf16(k0, aq0, z, 0, 0, 0);
      z = __builtin_amdgcn_mfma_f32_16x16x32_bf16(k1, aq1, z, 0, 0, 0);
      s[cf] = z;
    }

    // softmax: raw exp2 (bounded args), row-sum in-lane + 2 shfl, raw rcp
    float rs = 0.f;
#pragma unroll
    for (int cf = 0; cf < 16; ++cf)
#pragma unroll
      for (int q = 0; q < 4; ++q) {
        float p = __builtin_amdgcn_exp2f(s[cf][q] * cexp);
        s[cf][q] = p;
        rs += p;
      }
    rs += __shfl_xor(rs, 16, 64);
    rs += __shfl_xor(rs, 32, 64);
    const float rinv = __builtin_amdgcn_rcpf(rs);

    // P (unnormalized) -> W as [16][256], swizzled (wave-private; no barrier)
    const int pbase = lo * 256;
#pragma unroll
    for (int cf = 0; cf < 16; ++cf) {
      unsigned int u0 = cvtpk_bf16(s[cf][0], s[cf][1]);
      unsigned int u1 = cvtpk_bf16(s[cf][2], s[cf][3]);
      const int g16 = (cf * 2 + (hi4 >> 1)) ^ lo7;
      uint2 u; u.x = u0; u.y = u1;
      *(uint2*)&W[pbase + g16 * 8 + (hi4 & 1) * 4] = u;
    }

    // O = P @ V : A = P from W, B = V fragments from Vg (L2-hot)
    f32x4 o[4];
#pragma unroll
    for (int nf = 0; nf < 4; ++nf) o[nf] = (f32x4){0.f, 0.f, 0.f, 0.f};
#pragma unroll
    for (int kk = 0; kk < 8; ++kk) {
      const int g = (4 * kk + hi4) ^ lo7;
      short8 ap = *(const short8*)&W[pbase + g * 8];
#pragma unroll
      for (int nf = 0; nf < 4; ++nf) {
        short8 bv = *(const short8*)&vgb[(kk * 4 + nf) * 512];
        o[nf] = __builtin_amdgcn_mfma_f32_16x16x32_bf16(ap, bv, o[nf], 0, 0, 0);
      }
    }

    // normalize (deferred) + AO store
    float rq[4];
#pragma unroll
    for (int q = 0; q < 4; ++q) rq[q] = __shfl(rinv, (hi4 << 2) + q, 64);
    const long orow0 = rowb + st * 16 + (hi4 << 2);
    const int ocol = h * HD + lo;
#pragma unroll
    for (int nf = 0; nf < 4; ++nf) {
      unsigned int u0 = cvtpk_bf16(o[nf][0] * rq[0], o[nf][1] * rq[1]);
      unsigned int u1 = cvtpk_bf16(o[nf][2] * rq[2], o[nf][3] * rq[3]);
      AO[(orow0 + 0) * DIM + ocol + nf * 16] = (unsigned short)u0;
      AO[(orow0 + 1) * DIM + ocol + nf * 16] = (unsigned short)(u0 >> 16);
      AO[(orow0 + 2) * DIM + ocol + nf * 16] = (unsigned short)u1;
      AO[(orow0 + 3) * DIM + ocol + nf * 16] = (unsigned short)(u1 >> 16);
    }
  }
}

// ---------------- 256x256 big GEMM, r9 4-phase schedule: out-projection ----------------
template <int OUTMODE>
__global__ __launch_bounds__(512, 2) void gemm256(const unsigned short* __restrict__ A,
                                                  const unsigned short* __restrict__ B,
                                                  void* __restrict__ Cout,
                                                  int M, int N, int K, int nbx) {
  __shared__ unsigned short As[2][256 * 64];
  __shared__ unsigned short Bs[2][256 * 64];
  const int tid  = threadIdx.x;
  const int lane = tid & 63;
  const int wid  = tid >> 6;
  const int wr = wid >> 2;
  const int wc = wid & 3;
  const int lo = lane & 15, hi4 = lane >> 4, lo7 = lane & 7;

  const int nwg = gridDim.x;
  const int cpx = nwg >> 3;
  int flat = blockIdx.x;
  flat = (flat & 7) * cpx + (flat >> 3);
  const int bx = flat % nbx;
  const int by = flat / nbx;

  const long arow0 = (long)by * 256;
  const long brow0 = (long)bx * 256;
  const int nt = K >> 6;
  const int nj = nt >> 1;

  auto stageA = [&](int buf, int t) {
#pragma unroll
    for (int li = 0; li < 4; ++li) {
      int gi = li * 512 + tid;
      int row = gi >> 3;
      int cg = (gi & 7) ^ (row & 7);
      __builtin_amdgcn_global_load_lds(
          (const AS1 unsigned int*)&A[(arow0 + row) * K + (t << 6) + cg * 8],
          (AS3 unsigned int*)&As[buf][gi * 8], 16, 0, 0);
    }
  };
  auto stageB = [&](int buf, int t) {
#pragma unroll
    for (int li = 0; li < 4; ++li) {
      int gi = li * 512 + tid;
      int row = gi >> 3;
      int cg = (gi & 7) ^ (row & 7);
      __builtin_amdgcn_global_load_lds(
          (const AS1 unsigned int*)&B[(brow0 + row) * K + (t << 6) + cg * 8],
          (AS3 unsigned int*)&Bs[buf][gi * 8], 16, 0, 0);
    }
  };

  f32x4 acc[8][4];
#pragma unroll
  for (int i = 0; i < 8; ++i)
#pragma unroll
    for (int j = 0; j < 4; ++j) acc[i][j] = (f32x4){0.f, 0.f, 0.f, 0.f};

  stageA(0, 0);
  stageB(0, 0);
  stageB(1, 1);

  for (int j = 0; j < nj; ++j) {
    const int p = 2 * j;
    const bool more = (j + 1 < nj);
    short8 b[4][2];

    asm volatile("s_waitcnt vmcnt(4)" ::: "memory");
    __builtin_amdgcn_sched_barrier(0);
    __builtin_amdgcn_s_barrier();
    {
      short8 a[4][2];
#pragma unroll
      for (int nf = 0; nf < 4; ++nf)
#pragma unroll
        for (int kk = 0; kk < 2; ++kk) {
          const int row = wc * 64 + nf * 16 + lo;
          b[nf][kk] = *(const short8*)&Bs[0][row * 64 + ((kk * 4 + hi4) ^ lo7) * 8];
        }
#pragma unroll
      for (int mf = 0; mf < 4; ++mf)
#pragma unroll
        for (int kk = 0; kk < 2; ++kk) {
          const int row = wr * 128 + mf * 16 + lo;
          a[mf][kk] = *(const short8*)&As[0][row * 64 + ((kk * 4 + hi4) ^ lo7) * 8];
        }
      stageA(1, p + 1);
      __builtin_amdgcn_s_barrier();
      asm volatile("s_waitcnt lgkmcnt(0)" ::: "memory");
      __builtin_amdgcn_s_setprio(1);
#pragma unroll
      for (int kk = 0; kk < 2; ++kk)
#pragma unroll
        for (int mf = 0; mf < 4; ++mf)
#pragma unroll
          for (int nf = 0; nf < 4; ++nf)
            acc[mf][nf] = __builtin_amdgcn_mfma_f32_16x16x32_bf16(a[mf][kk], b[nf][kk], acc[mf][nf], 0, 0, 0);
      __builtin_amdgcn_s_setprio(0);
    }
    {
      short8 a[4][2];
#pragma unroll
      for (int mf = 0; mf < 4; ++mf)
#pragma unroll
        for (int kk = 0; kk < 2; ++kk) {
          const int row = wr * 128 + (mf + 4) * 16 + lo;
          a[mf][kk] = *(const short8*)&As[0][row * 64 + ((kk * 4 + hi4) ^ lo7) * 8];
        }
      if (more) stageB(0, p + 2);
      __builtin_amdgcn_s_barrier();
      asm volatile("s_waitcnt lgkmcnt(0)" ::: "memory");
      __builtin_amdgcn_s_setprio(1);
#pragma unroll
      for (int kk = 0; kk < 2; ++kk)
#pragma unroll
        for (int mf = 0; mf < 4; ++mf)
#pragma unroll
          for (int nf = 0; nf < 4; ++nf)
            acc[mf + 4][nf] = __builtin_amdgcn_mfma_f32_16x16x32_bf16(a[mf][kk], b[nf][kk], acc[mf + 4][nf], 0, 0, 0);
      __builtin_amdgcn_s_setprio(0);
    }
    if (more) asm volatile("s_waitcnt vmcnt(4)" ::: "memory");
    else      asm volatile("s_waitcnt vmcnt(0)" ::: "memory");
    __builtin_amdgcn_sched_barrier(0);
    __builtin_amdgcn_s_barrier();
    {
      short8 a[4][2];
#pragma unroll
      for (int nf = 0; nf < 4; ++nf)
#pragma unroll
        for (int kk = 0; kk < 2; ++kk) {
          const int row = wc * 64 + nf * 16 + lo;
          b[nf][kk] = *(const short8*)&Bs[1][row * 64 + ((kk * 4 + hi4) ^ lo7) * 8];
        }
#pragma unroll
      for (int mf = 0; mf < 4; ++mf)
#pragma unroll
        for (int kk = 0; kk < 2; ++kk) {
          const int row = wr * 128 + mf * 16 + lo;
          a[mf][kk] = *(const short8*)&As[1][row * 64 + ((kk * 4 + hi4) ^ lo7) * 8];
        }
      if (more) stageA(0, p + 2);
      __builtin_amdgcn_s_barrier();
      asm volatile("s_waitcnt lgkmcnt(0)" ::: "memory");
      __builtin_amdgcn_s_setprio(1);
#pragma unroll
      for (int kk = 0; kk < 2; ++kk)
#pragma unroll
        for (int mf = 0; mf < 4; ++mf)
#pragma unroll
          for (int nf = 0; nf < 4; ++nf)
            acc[mf][nf] = __builtin_amdgcn_mfma_f32_16x16x32_bf16(a[mf][kk], b[nf][kk], acc[mf][nf], 0, 0, 0);
      __builtin_amdgcn_s_setprio(0);
    }
    {
      short8 a[4][2];
#pragma unroll
      for (int mf = 0; mf < 4; ++mf)
#pragma unroll
        for (int kk = 0; kk < 2; ++kk) {
          const int row = wr * 128 + (mf + 4) * 16 + lo;
          a[mf][kk] = *(const short8*)&As[1][row * 64 + ((kk * 4 + hi4) ^ lo7) * 8];
        }
      if (more) stageB(1, p + 3);
      __builtin_amdgcn_s_barrier();
      asm volatile("s_waitcnt lgkmcnt(0)" ::: "memory");
      __builtin_amdgcn_s_setprio(1);
#pragma unroll
      for (int kk = 0; kk < 2; ++kk)
#pragma unroll
        for (int mf = 0; mf < 4; ++mf)
#pragma unroll
          for (int nf = 0; nf < 4; ++nf)
            acc[mf + 4][nf] = __builtin_amdgcn_mfma_f32_16x16x32_bf16(a[mf][kk], b[nf][kk], acc[mf + 4][nf], 0, 0, 0);
      __builtin_amdgcn_s_setprio(0);
    }
  }

  const long row0 = (long)by * 256 + wr * 128 + (hi4 << 2);
  const long col0 = (long)bx * 256 + wc * 64 + lo;
  if (OUTMODE == 1) {
    float* C = (float*)Cout;
#pragma unroll
    for (int mf = 0; mf < 8; ++mf)
#pragma unroll
      for (int q = 0; q < 4; ++q) {
        float* cp = &C[(row0 + mf * 16 + q) * N + col0];
#pragma unroll
        for (int nf = 0; nf < 4; ++nf) cp[nf * 16] = acc[mf][nf][q];
      }
  } else {
    unsigned short* C = (unsigned short*)Cout;
#pragma unroll
    for (int mf = 0; mf < 8; ++mf)
#pragma unroll
      for (int q = 0; q < 4; ++q) {
        unsigned short* cp = &C[(row0 + mf * 16 + q) * N + col0];
#pragma unroll
        for (int nf = 0; nf < 4; ++nf) cp[nf * 16] = f2bf(acc[mf][nf][q]);
      }
  }
}

extern "C" void kernel_launch(void* const* d_in, const int* in_sizes, int n_in,
                              void* d_out, int out_size, void* d_ws, size_t ws_size,
                              hipStream_t stream) {
  (void)in_sizes; (void)n_in; (void)out_size; (void)ws_size;
  const float* x    = (const float*)d_in[0];
  const float* kv   = (const float*)d_in[1];
  // d_in[2] = rope_bias, d_in[7] = Wrope: bias constant over softmax axis -> unused.
  const float* Wq   = (const float*)d_in[3];
  const float* Wk   = (const float*)d_in[4];
  const float* Wv   = (const float*)d_in[5];
  const float* Wout = (const float*)d_in[6];
  float* out = (float*)d_out;

  char* ws = (char*)d_ws;
  unsigned short* xb  = (unsigned short*)(ws);                 // 64 MB
  unsigned short* AOb = (unsigned short*)(ws + 67108864);      // 64 MB attn output
  unsigned short* wqb = (unsigned short*)(ws + 134217728);     // 2 MB each
  unsigned short* wkb = (unsigned short*)(ws + 136314880);
  unsigned short* wvb = (unsigned short*)(ws + 138412032);
  unsigned short* wob = (unsigned short*)(ws + 140509184);
  unsigned short* kvb = (unsigned short*)(ws + 142606336);     // 0.5 MB
  unsigned short* Kgb = (unsigned short*)(ws + 143130624);     // 0.5 MB (K A-frag layout)
  unsigned short* Vgb = (unsigned short*)(ws + 144179200);     // 0.5 MB (V B-frag layout)

  cvt_kernel<<<2048, 256, 0, stream>>>(x, xb, (N_TOK * DIM) / 4);
  cvt_multi<<<dim3(128, 5), 256, 0, stream>>>(Wq, Wk, Wv, Wout, kv,
                                              wqb, wkb, wvb, wob, kvb);

  gemm_bt<4><<<dim3(8, 2), 256, 0, stream>>>(kvb, wkb, Kgb, CTX, DIM, DIM);
  gemm_bt<3><<<dim3(8, 2), 256, 0, stream>>>(kvb, wvb, Vgb, CTX, DIM, DIM);

  // fused Q-projection + attention (writes AOb)
  gemm256_qattn<<<512, 512, 0, stream>>>(xb, wqb, Kgb, Vgb, AOb,
                                         N_TOK, DIM, DIM, DIM / 256);

  // output projection (f32 out)
  gemm256<1><<<512, 512, 0, stream>>>(AOb, wob, out, N_TOK, DIM, DIM, DIM / 256);
}

// Round 16
// 280.021 us; speedup vs baseline: 1.2030x; 1.2030x over previous
//
#include <hip/hip_runtime.h>
#include <hip/hip_bf16.h>
#include <cstdint>

#define N_TOK 32768
#define CTX   256
#define DIM   1024
#define NH    16
#define HD    64

typedef __attribute__((ext_vector_type(8))) short short8;
typedef __attribute__((ext_vector_type(4))) float f32x4;
typedef __attribute__((ext_vector_type(4))) unsigned short ushort4v;

#define AS1 __attribute__((address_space(1)))
#define AS3 __attribute__((address_space(3)))

__device__ inline unsigned short f2bf(float f) {
  union { float f; unsigned int u; } v; v.f = f;
  unsigned int r = v.u + 0x7fffu + ((v.u >> 16) & 1u);
  return (unsigned short)(r >> 16);
}

__device__ inline unsigned int cvtpk_bf16(float a, float b) {
  unsigned int r;
  asm("v_cvt_pk_bf16_f32 %0, %1, %2" : "=v"(r) : "v"(a), "v"(b));
  return r;  // low16 = bf16(a), high16 = bf16(b)
}

// ---------------- ALL f32 -> bf16 converts in one launch (grid-partitioned) ----------------
// blocks [0,2048): x (8M elems); [2048,2176): Wq; [2176,2304): Wk; [2304,2432): Wv;
// [2432,2560): Wout; [2560,2624): kv.
__global__ void cvt_all(const float* __restrict__ x,  const float* __restrict__ w0,
                        const float* __restrict__ w1, const float* __restrict__ w2,
                        const float* __restrict__ w3, const float* __restrict__ kv,
                        unsigned short* __restrict__ dx, unsigned short* __restrict__ e0,
                        unsigned short* __restrict__ e1, unsigned short* __restrict__ e2,
                        unsigned short* __restrict__ e3, unsigned short* __restrict__ dkv) {
  const int b = blockIdx.x;
  const float* s; unsigned short* d; int n4, b0, nb;
  if (b < 2048)      { s = x;  d = dx;  n4 = (N_TOK * DIM) / 4; b0 = 0;    nb = 2048; }
  else if (b < 2176) { s = w0; d = e0;  n4 = (DIM * DIM) / 4;   b0 = 2048; nb = 128; }
  else if (b < 2304) { s = w1; d = e1;  n4 = (DIM * DIM) / 4;   b0 = 2176; nb = 128; }
  else if (b < 2432) { s = w2; d = e2;  n4 = (DIM * DIM) / 4;   b0 = 2304; nb = 128; }
  else if (b < 2560) { s = w3; d = e3;  n4 = (DIM * DIM) / 4;   b0 = 2432; nb = 128; }
  else               { s = kv; d = dkv; n4 = (CTX * DIM) / 4;   b0 = 2560; nb = 64; }
  const int stride = nb * 256;
  for (int j = (b - b0) * 256 + threadIdx.x; j < n4; j += stride) {
    float4 v = reinterpret_cast<const float4*>(s)[j];
    ushort4v o;
    o.x = f2bf(v.x); o.y = f2bf(v.y); o.z = f2bf(v.z); o.w = f2bf(v.w);
    reinterpret_cast<ushort4v*>(d)[j] = o;
  }
}

// ---------------- K and V projections in ONE launch (z = 0: K row-major; 1: V frag) ----------------
__global__ __launch_bounds__(256) void kvproj(const unsigned short* __restrict__ Akv,
                                              const unsigned short* __restrict__ Wk,
                                              const unsigned short* __restrict__ Wv,
                                              unsigned short* __restrict__ Kb,
                                              unsigned short* __restrict__ Vg) {
  __shared__ unsigned short As[128 * 32];
  __shared__ unsigned short Bs[128 * 32];
  const int tid  = threadIdx.x;
  const int lane = tid & 63;
  const int wid  = tid >> 6;
  const int wr = wid >> 1, wc = wid & 1;
  const int bx = blockIdx.x, by = blockIdx.y;
  const bool isV = (blockIdx.z != 0);
  const unsigned short* B = isV ? Wv : Wk;
  const long arow0 = (long)by * 128;
  const long brow0 = (long)bx * 128;
  const int sr = tid >> 2;
  const int sc = (tid & 3) * 8;
  const int K = DIM, N = DIM;

  f32x4 acc[4][4];
#pragma unroll
  for (int i = 0; i < 4; ++i)
#pragma unroll
    for (int j = 0; j < 4; ++j) acc[i][j] = (f32x4){0.f, 0.f, 0.f, 0.f};

  const int ar = wr * 64 + (lane & 15);
  const int br = wc * 64 + (lane & 15);
  const int kc = (lane >> 4) * 8;

  for (int k0 = 0; k0 < K; k0 += 32) {
#pragma unroll
    for (int pass = 0; pass < 2; ++pass) {
      int r = pass * 64 + sr;
      const unsigned short* ga = &Akv[(arow0 + r) * K + k0 + sc];
      const unsigned short* gb = &B[(brow0 + r) * K + k0 + sc];
      __builtin_amdgcn_global_load_lds((const AS1 unsigned int*)ga,
                                       (AS3 unsigned int*)&As[(size_t)tid * 8 + pass * 2048], 16, 0, 0);
      __builtin_amdgcn_global_load_lds((const AS1 unsigned int*)gb,
                                       (AS3 unsigned int*)&Bs[(size_t)tid * 8 + pass * 2048], 16, 0, 0);
    }
    __syncthreads();
    short8 a[4], b[4];
#pragma unroll
    for (int mf = 0; mf < 4; ++mf) a[mf] = *(const short8*)&As[(ar + mf * 16) * 32 + kc];
#pragma unroll
    for (int nf = 0; nf < 4; ++nf) b[nf] = *(const short8*)&Bs[(br + nf * 16) * 32 + kc];
#pragma unroll
    for (int mf = 0; mf < 4; ++mf)
#pragma unroll
      for (int nf = 0; nf < 4; ++nf)
        acc[mf][nf] = __builtin_amdgcn_mfma_f32_16x16x32_bf16(a[mf], b[nf], acc[mf][nf], 0, 0, 0);
    __syncthreads();
  }

  const long row0 = (long)by * 128 + wr * 64 + ((lane >> 4) << 2);
  const long col0 = (long)bx * 128 + wc * 64 + (lane & 15);
  if (!isV) {
#pragma unroll
    for (int mf = 0; mf < 4; ++mf)
#pragma unroll
      for (int q = 0; q < 4; ++q) {
        unsigned short* cp = &Kb[(row0 + mf * 16 + q) * N + col0];
#pragma unroll
        for (int nf = 0; nf < 4; ++nf) cp[nf * 16] = f2bf(acc[mf][nf][q]);
      }
  } else {
#pragma unroll
    for (int mf = 0; mf < 4; ++mf)
#pragma unroll
      for (int q = 0; q < 4; ++q) {
        const int c = (int)(row0 + mf * 16 + q);
#pragma unroll
        for (int nf = 0; nf < 4; ++nf) {
          const int dcol = (int)(col0 + nf * 16);
          const size_t off = (size_t)(dcol >> 6) * 16384 +
                             (size_t)((c >> 5) * 4 + ((dcol >> 4) & 3)) * 512 +
                             (size_t)(((c >> 3) & 3) * 16 + (dcol & 15)) * 8 +
                             (size_t)(c & 7);
          Vg[off] = f2bf(acc[mf][nf][q]);
        }
      }
  }
}

// ---------------- 256x256 big GEMM, r9 4-phase schedule (proven 78us) ----------------
template <int OUTMODE>
__global__ __launch_bounds__(512, 2) void gemm256(const unsigned short* __restrict__ A,
                                                  const unsigned short* __restrict__ B,
                                                  void* __restrict__ Cout,
                                                  int M, int N, int K, int nbx) {
  __shared__ unsigned short As[2][256 * 64];
  __shared__ unsigned short Bs[2][256 * 64];
  const int tid  = threadIdx.x;
  const int lane = tid & 63;
  const int wid  = tid >> 6;
  const int wr = wid >> 2;
  const int wc = wid & 3;
  const int lo = lane & 15, hi4 = lane >> 4, lo7 = lane & 7;

  const int nwg = gridDim.x;
  const int cpx = nwg >> 3;
  int flat = blockIdx.x;
  flat = (flat & 7) * cpx + (flat >> 3);
  const int bx = flat % nbx;
  const int by = flat / nbx;

  const long arow0 = (long)by * 256;
  const long brow0 = (long)bx * 256;
  const int nt = K >> 6;
  const int nj = nt >> 1;

  auto stageA = [&](int buf, int t) {
#pragma unroll
    for (int li = 0; li < 4; ++li) {
      int gi = li * 512 + tid;
      int row = gi >> 3;
      int cg = (gi & 7) ^ (row & 7);
      __builtin_amdgcn_global_load_lds(
          (const AS1 unsigned int*)&A[(arow0 + row) * K + (t << 6) + cg * 8],
          (AS3 unsigned int*)&As[buf][gi * 8], 16, 0, 0);
    }
  };
  auto stageB = [&](int buf, int t) {
#pragma unroll
    for (int li = 0; li < 4; ++li) {
      int gi = li * 512 + tid;
      int row = gi >> 3;
      int cg = (gi & 7) ^ (row & 7);
      __builtin_amdgcn_global_load_lds(
          (const AS1 unsigned int*)&B[(brow0 + row) * K + (t << 6) + cg * 8],
          (AS3 unsigned int*)&Bs[buf][gi * 8], 16, 0, 0);
    }
  };

  f32x4 acc[8][4];
#pragma unroll
  for (int i = 0; i < 8; ++i)
#pragma unroll
    for (int j = 0; j < 4; ++j) acc[i][j] = (f32x4){0.f, 0.f, 0.f, 0.f};

  stageA(0, 0);
  stageB(0, 0);
  stageB(1, 1);

  for (int j = 0; j < nj; ++j) {
    const int p = 2 * j;
    const bool more = (j + 1 < nj);
    short8 b[4][2];

    asm volatile("s_waitcnt vmcnt(4)" ::: "memory");
    __builtin_amdgcn_sched_barrier(0);
    __builtin_amdgcn_s_barrier();
    {
      short8 a[4][2];
#pragma unroll
      for (int nf = 0; nf < 4; ++nf)
#pragma unroll
        for (int kk = 0; kk < 2; ++kk) {
          const int row = wc * 64 + nf * 16 + lo;
          b[nf][kk] = *(const short8*)&Bs[0][row * 64 + ((kk * 4 + hi4) ^ lo7) * 8];
        }
#pragma unroll
      for (int mf = 0; mf < 4; ++mf)
#pragma unroll
        for (int kk = 0; kk < 2; ++kk) {
          const int row = wr * 128 + mf * 16 + lo;
          a[mf][kk] = *(const short8*)&As[0][row * 64 + ((kk * 4 + hi4) ^ lo7) * 8];
        }
      stageA(1, p + 1);
      __builtin_amdgcn_s_barrier();
      asm volatile("s_waitcnt lgkmcnt(0)" ::: "memory");
      __builtin_amdgcn_s_setprio(1);
#pragma unroll
      for (int kk = 0; kk < 2; ++kk)
#pragma unroll
        for (int mf = 0; mf < 4; ++mf)
#pragma unroll
          for (int nf = 0; nf < 4; ++nf)
            acc[mf][nf] = __builtin_amdgcn_mfma_f32_16x16x32_bf16(a[mf][kk], b[nf][kk], acc[mf][nf], 0, 0, 0);
      __builtin_amdgcn_s_setprio(0);
    }
    {
      short8 a[4][2];
#pragma unroll
      for (int mf = 0; mf < 4; ++mf)
#pragma unroll
        for (int kk = 0; kk < 2; ++kk) {
          const int row = wr * 128 + (mf + 4) * 16 + lo;
          a[mf][kk] = *(const short8*)&As[0][row * 64 + ((kk * 4 + hi4) ^ lo7) * 8];
        }
      if (more) stageB(0, p + 2);
      __builtin_amdgcn_s_barrier();
      asm volatile("s_waitcnt lgkmcnt(0)" ::: "memory");
      __builtin_amdgcn_s_setprio(1);
#pragma unroll
      for (int kk = 0; kk < 2; ++kk)
#pragma unroll
        for (int mf = 0; mf < 4; ++mf)
#pragma unroll
          for (int nf = 0; nf < 4; ++nf)
            acc[mf + 4][nf] = __builtin_amdgcn_mfma_f32_16x16x32_bf16(a[mf][kk], b[nf][kk], acc[mf + 4][nf], 0, 0, 0);
      __builtin_amdgcn_s_setprio(0);
    }
    if (more) asm volatile("s_waitcnt vmcnt(4)" ::: "memory");
    else      asm volatile("s_waitcnt vmcnt(0)" ::: "memory");
    __builtin_amdgcn_sched_barrier(0);
    __builtin_amdgcn_s_barrier();
    {
      short8 a[4][2];
#pragma unroll
      for (int nf = 0; nf < 4; ++nf)
#pragma unroll
        for (int kk = 0; kk < 2; ++kk) {
          const int row = wc * 64 + nf * 16 + lo;
          b[nf][kk] = *(const short8*)&Bs[1][row * 64 + ((kk * 4 + hi4) ^ lo7) * 8];
        }
#pragma unroll
      for (int mf = 0; mf < 4; ++mf)
#pragma unroll
        for (int kk = 0; kk < 2; ++kk) {
          const int row = wr * 128 + mf * 16 + lo;
          a[mf][kk] = *(const short8*)&As[1][row * 64 + ((kk * 4 + hi4) ^ lo7) * 8];
        }
      if (more) stageA(0, p + 2);
      __builtin_amdgcn_s_barrier();
      asm volatile("s_waitcnt lgkmcnt(0)" ::: "memory");
      __builtin_amdgcn_s_setprio(1);
#pragma unroll
      for (int kk = 0; kk < 2; ++kk)
#pragma unroll
        for (int mf = 0; mf < 4; ++mf)
#pragma unroll
          for (int nf = 0; nf < 4; ++nf)
            acc[mf][nf] = __builtin_amdgcn_mfma_f32_16x16x32_bf16(a[mf][kk], b[nf][kk], acc[mf][nf], 0, 0, 0);
      __builtin_amdgcn_s_setprio(0);
    }
    {
      short8 a[4][2];
#pragma unroll
      for (int mf = 0; mf < 4; ++mf)
#pragma unroll
        for (int kk = 0; kk < 2; ++kk) {
          const int row = wr * 128 + (mf + 4) * 16 + lo;
          a[mf][kk] = *(const short8*)&As[1][row * 64 + ((kk * 4 + hi4) ^ lo7) * 8];
        }
      if (more) stageB(1, p + 3);
      __builtin_amdgcn_s_barrier();
      asm volatile("s_waitcnt lgkmcnt(0)" ::: "memory");
      __builtin_amdgcn_s_setprio(1);
#pragma unroll
      for (int kk = 0; kk < 2; ++kk)
#pragma unroll
        for (int mf = 0; mf < 4; ++mf)
#pragma unroll
          for (int nf = 0; nf < 4; ++nf)
            acc[mf + 4][nf] = __builtin_amdgcn_mfma_f32_16x16x32_bf16(a[mf][kk], b[nf][kk], acc[mf + 4][nf], 0, 0, 0);
      __builtin_amdgcn_s_setprio(0);
    }
  }

  const long row0 = (long)by * 256 + wr * 128 + (hi4 << 2);
  const long col0 = (long)bx * 256 + wc * 64 + lo;
  if (OUTMODE == 1) {
    float* C = (float*)Cout;
#pragma unroll
    for (int mf = 0; mf < 8; ++mf)
#pragma unroll
      for (int q = 0; q < 4; ++q) {
        float* cp = &C[(row0 + mf * 16 + q) * N + col0];
#pragma unroll
        for (int nf = 0; nf < 4; ++nf) cp[nf * 16] = acc[mf][nf][q];
      }
  } else {
    unsigned short* C = (unsigned short*)Cout;
#pragma unroll
    for (int mf = 0; mf < 8; ++mf)
#pragma unroll
      for (int q = 0; q < 4; ++q) {
        unsigned short* cp = &C[(row0 + mf * 16 + q) * N + col0];
#pragma unroll
        for (int nf = 0; nf < 4; ++nf) cp[nf * 16] = f2bf(acc[mf][nf][q]);
      }
  }
}

// ---------------- fused attention (r11 structure: session-best) ----------------
__global__ __launch_bounds__(256) void attn_kernel(const unsigned short* __restrict__ Q,
                                                   const unsigned short* __restrict__ Kc,
                                                   const unsigned short* __restrict__ Vg,
                                                   unsigned short* __restrict__ AO) {
  __shared__ unsigned short SH[256 * 64];  // K[c][d] then P[q][c] (32KB union)
  const int tid = threadIdx.x, lane = tid & 63, wid = tid >> 6;
  const int lo = lane & 15, hi4 = lane >> 4, lo7 = lane & 7;
  const int h = blockIdx.y;
  const int n0 = blockIdx.x * 64;

#pragma unroll
  for (int p = 0; p < 8; ++p) {
    int gi = p * 256 + tid;
    int c  = gi >> 3;
    int gp = gi & 7;
    const unsigned short* src = &Kc[(size_t)c * DIM + h * HD + ((gp ^ (c & 7)) << 3)];
    __builtin_amdgcn_global_load_lds((const AS1 unsigned int*)src,
                                     (AS3 unsigned int*)&SH[gi * 8], 16, 0, 0);
  }

  const int qrow = n0 + wid * 16 + lo;
  const int kc = hi4 * 8;
  short8 aq0 = *(const short8*)&Q[(size_t)qrow * DIM + h * HD + kc];
  short8 aq1 = *(const short8*)&Q[(size_t)qrow * DIM + h * HD + 32 + kc];

  asm volatile("s_waitcnt vmcnt(0)" ::: "memory");
  __builtin_amdgcn_sched_barrier(0);
  __builtin_amdgcn_s_barrier();
  __builtin_amdgcn_sched_barrier(0);

  const int g0 = hi4 ^ lo7;
  f32x4 s[16];
#pragma unroll
  for (int cf = 0; cf < 16; ++cf) {
    const int r = cf * 16 + lo;
    short8 b0 = *(const short8*)&SH[r * 64 + g0 * 8];
    short8 b1 = *(const short8*)&SH[r * 64 + (g0 ^ 4) * 8];
    f32x4 z = (f32x4){0.f, 0.f, 0.f, 0.f};
    z = __builtin_amdgcn_mfma_f32_16x16x32_bf16(b0, aq0, z, 0, 0, 0);
    z = __builtin_amdgcn_mfma_f32_16x16x32_bf16(b1, aq1, z, 0, 0, 0);
    s[cf] = z;
  }

  const float cexp = 0.125f * 1.44269504088896f;  // SCALE * log2(e)
  float rs = 0.f;
#pragma unroll
  for (int cf = 0; cf < 16; ++cf)
#pragma unroll
    for (int q = 0; q < 4; ++q) {
      float p = __builtin_amdgcn_exp2f(s[cf][q] * cexp);
      s[cf][q] = p;
      rs += p;
    }
  rs += __shfl_xor(rs, 16, 64);
  rs += __shfl_xor(rs, 32, 64);
  const float rinv = __builtin_amdgcn_rcpf(rs);

  __builtin_amdgcn_s_barrier();   // all waves' K reads complete before P overwrites SH

  const unsigned short* vb = &Vg[(size_t)h * 16384 + (size_t)lane * 8];
  short8 bv0[4];
#pragma unroll
  for (int nf = 0; nf < 4; ++nf) bv0[nf] = *(const short8*)&vb[nf * 512];

  const int pbase = (wid * 16 + lo) * 256;
  const int rx    = lo7;
#pragma unroll
  for (int cf = 0; cf < 16; ++cf) {
    unsigned int u0 = cvtpk_bf16(s[cf][0], s[cf][1]);
    unsigned int u1 = cvtpk_bf16(s[cf][2], s[cf][3]);
    const int g16 = (cf * 2 + (hi4 >> 1)) ^ rx;
    uint2 u; u.x = u0; u.y = u1;
    *(uint2*)&SH[pbase + g16 * 8 + (hi4 & 1) * 4] = u;
  }

  f32x4 o[4];
#pragma unroll
  for (int nf = 0; nf < 4; ++nf) o[nf] = (f32x4){0.f, 0.f, 0.f, 0.f};
#pragma unroll
  for (int kk = 0; kk < 8; ++kk) {
    const int g = (4 * kk + hi4) ^ lo7;
    short8 ap = *(const short8*)&SH[pbase + g * 8];
#pragma unroll
    for (int nf = 0; nf < 4; ++nf) {
      short8 bv = (kk == 0) ? bv0[nf] : *(const short8*)&vb[(kk * 4 + nf) * 512];
      o[nf] = __builtin_amdgcn_mfma_f32_16x16x32_bf16(ap, bv, o[nf], 0, 0, 0);
    }
  }

  float rq[4];
#pragma unroll
  for (int q = 0; q < 4; ++q) rq[q] = __shfl(rinv, (hi4 << 2) + q, 64);
  const size_t orow0 = n0 + wid * 16 + (hi4 << 2);
  const int ocol = h * HD + lo;
#pragma unroll
  for (int nf = 0; nf < 4; ++nf) {
    unsigned int u0 = cvtpk_bf16(o[nf][0] * rq[0], o[nf][1] * rq[1]);
    unsigned int u1 = cvtpk_bf16(o[nf][2] * rq[2], o[nf][3] * rq[3]);
    AO[(orow0 + 0) * DIM + ocol + nf * 16] = (unsigned short)u0;
    AO[(orow0 + 1) * DIM + ocol + nf * 16] = (unsigned short)(u0 >> 16);
    AO[(orow0 + 2) * DIM + ocol + nf * 16] = (unsigned short)u1;
    AO[(orow0 + 3) * DIM + ocol + nf * 16] = (unsigned short)(u1 >> 16);
  }
}

extern "C" void kernel_launch(void* const* d_in, const int* in_sizes, int n_in,
                              void* d_out, int out_size, void* d_ws, size_t ws_size,
                              hipStream_t stream) {
  (void)in_sizes; (void)n_in; (void)out_size; (void)ws_size;
  const float* x    = (const float*)d_in[0];
  const float* kv   = (const float*)d_in[1];
  // d_in[2] = rope_bias, d_in[7] = Wrope: bias constant over softmax axis -> unused.
  const float* Wq   = (const float*)d_in[3];
  const float* Wk   = (const float*)d_in[4];
  const float* Wv   = (const float*)d_in[5];
  const float* Wout = (const float*)d_in[6];
  float* out = (float*)d_out;

  char* ws = (char*)d_ws;
  unsigned short* xb  = (unsigned short*)(ws);                 // 64 MB
  unsigned short* Qb  = (unsigned short*)(ws + 67108864);      // 64 MB (reused as attn_out)
  unsigned short* wqb = (unsigned short*)(ws + 134217728);     // 2 MB each
  unsigned short* wkb = (unsigned short*)(ws + 136314880);
  unsigned short* wvb = (unsigned short*)(ws + 138412032);
  unsigned short* wob = (unsigned short*)(ws + 140509184);
  unsigned short* kvb = (unsigned short*)(ws + 142606336);     // 0.5 MB
  unsigned short* Kb  = (unsigned short*)(ws + 143130624);     // 0.5 MB (K row-major)
  unsigned short* Vgb = (unsigned short*)(ws + 144179200);     // 0.5 MB (V fragment layout)

  // all converts in one launch
  cvt_all<<<2624, 256, 0, stream>>>(x, Wq, Wk, Wv, Wout, kv,
                                    xb, wqb, wkb, wvb, wob, kvb);

  // K + V projections in one launch
  kvproj<<<dim3(8, 2, 2), 256, 0, stream>>>(kvb, wkb, wvb, Kb, Vgb);

  // Q projection: 256x256 tiles, grid = (32768/256)*(1024/256) = 512
  gemm256<0><<<512, 512, 0, stream>>>(xb, wqb, Qb, N_TOK, DIM, DIM, DIM / 256);

  // fused attention, in-place attn_out over Qb
  attn_kernel<<<dim3(N_TOK / 64, NH), 256, 0, stream>>>(Qb, Kb, Vgb, Qb);

  // output projection (f32 out)
  gemm256<1><<<512, 512, 0, stream>>>(Qb, wob, out, N_TOK, DIM, DIM, DIM / 256);
}

// Round 17
// 275.822 us; speedup vs baseline: 1.2213x; 1.0152x over previous
//
#include <hip/hip_runtime.h>
#include <hip/hip_bf16.h>
#include <cstdint>

#define N_TOK 32768
#define CTX   256
#define DIM   1024
#define NH    16
#define HD    64

typedef __attribute__((ext_vector_type(8))) short short8;
typedef __attribute__((ext_vector_type(4))) float f32x4;
typedef __attribute__((ext_vector_type(4))) unsigned short ushort4v;

#define AS1 __attribute__((address_space(1)))
#define AS3 __attribute__((address_space(3)))

__device__ inline unsigned short f2bf(float f) {
  union { float f; unsigned int u; } v; v.f = f;
  unsigned int r = v.u + 0x7fffu + ((v.u >> 16) & 1u);
  return (unsigned short)(r >> 16);
}

__device__ inline unsigned int cvtpk_bf16(float a, float b) {
  unsigned int r;
  asm("v_cvt_pk_bf16_f32 %0, %1, %2" : "=v"(r) : "v"(a), "v"(b));
  return r;  // low16 = bf16(a), high16 = bf16(b)
}

// ---------------- ALL f32 -> bf16 converts in one launch (grid-partitioned) ----------------
__global__ void cvt_all(const float* __restrict__ x,  const float* __restrict__ w0,
                        const float* __restrict__ w1, const float* __restrict__ w2,
                        const float* __restrict__ w3, const float* __restrict__ kv,
                        unsigned short* __restrict__ dx, unsigned short* __restrict__ e0,
                        unsigned short* __restrict__ e1, unsigned short* __restrict__ e2,
                        unsigned short* __restrict__ e3, unsigned short* __restrict__ dkv) {
  const int b = blockIdx.x;
  const float* s; unsigned short* d; int n4, b0, nb;
  if (b < 2048)      { s = x;  d = dx;  n4 = (N_TOK * DIM) / 4; b0 = 0;    nb = 2048; }
  else if (b < 2176) { s = w0; d = e0;  n4 = (DIM * DIM) / 4;   b0 = 2048; nb = 128; }
  else if (b < 2304) { s = w1; d = e1;  n4 = (DIM * DIM) / 4;   b0 = 2176; nb = 128; }
  else if (b < 2432) { s = w2; d = e2;  n4 = (DIM * DIM) / 4;   b0 = 2304; nb = 128; }
  else if (b < 2560) { s = w3; d = e3;  n4 = (DIM * DIM) / 4;   b0 = 2432; nb = 128; }
  else               { s = kv; d = dkv; n4 = (CTX * DIM) / 4;   b0 = 2560; nb = 64; }
  const int stride = nb * 256;
  for (int j = (b - b0) * 256 + threadIdx.x; j < n4; j += stride) {
    float4 v = reinterpret_cast<const float4*>(s)[j];
    ushort4v o;
    o.x = f2bf(v.x); o.y = f2bf(v.y); o.z = f2bf(v.z); o.w = f2bf(v.w);
    reinterpret_cast<ushort4v*>(d)[j] = o;
  }
}

// ---------------- K and V projections in ONE launch (z = 0: K row-major; 1: V frag) ----------------
__global__ __launch_bounds__(256) void kvproj(const unsigned short* __restrict__ Akv,
                                              const unsigned short* __restrict__ Wk,
                                              const unsigned short* __restrict__ Wv,
                                              unsigned short* __restrict__ Kb,
                                              unsigned short* __restrict__ Vg) {
  __shared__ unsigned short As[128 * 32];
  __shared__ unsigned short Bs[128 * 32];
  const int tid  = threadIdx.x;
  const int lane = tid & 63;
  const int wid  = tid >> 6;
  const int wr = wid >> 1, wc = wid & 1;
  const int bx = blockIdx.x, by = blockIdx.y;
  const bool isV = (blockIdx.z != 0);
  const unsigned short* B = isV ? Wv : Wk;
  const long arow0 = (long)by * 128;
  const long brow0 = (long)bx * 128;
  const int sr = tid >> 2;
  const int sc = (tid & 3) * 8;
  const int K = DIM, N = DIM;

  f32x4 acc[4][4];
#pragma unroll
  for (int i = 0; i < 4; ++i)
#pragma unroll
    for (int j = 0; j < 4; ++j) acc[i][j] = (f32x4){0.f, 0.f, 0.f, 0.f};

  const int ar = wr * 64 + (lane & 15);
  const int br = wc * 64 + (lane & 15);
  const int kc = (lane >> 4) * 8;

  for (int k0 = 0; k0 < K; k0 += 32) {
#pragma unroll
    for (int pass = 0; pass < 2; ++pass) {
      int r = pass * 64 + sr;
      const unsigned short* ga = &Akv[(arow0 + r) * K + k0 + sc];
      const unsigned short* gb = &B[(brow0 + r) * K + k0 + sc];
      __builtin_amdgcn_global_load_lds((const AS1 unsigned int*)ga,
                                       (AS3 unsigned int*)&As[(size_t)tid * 8 + pass * 2048], 16, 0, 0);
      __builtin_amdgcn_global_load_lds((const AS1 unsigned int*)gb,
                                       (AS3 unsigned int*)&Bs[(size_t)tid * 8 + pass * 2048], 16, 0, 0);
    }
    __syncthreads();
    short8 a[4], b[4];
#pragma unroll
    for (int mf = 0; mf < 4; ++mf) a[mf] = *(const short8*)&As[(ar + mf * 16) * 32 + kc];
#pragma unroll
    for (int nf = 0; nf < 4; ++nf) b[nf] = *(const short8*)&Bs[(br + nf * 16) * 32 + kc];
#pragma unroll
    for (int mf = 0; mf < 4; ++mf)
#pragma unroll
      for (int nf = 0; nf < 4; ++nf)
        acc[mf][nf] = __builtin_amdgcn_mfma_f32_16x16x32_bf16(a[mf], b[nf], acc[mf][nf], 0, 0, 0);
    __syncthreads();
  }

  const long row0 = (long)by * 128 + wr * 64 + ((lane >> 4) << 2);
  const long col0 = (long)bx * 128 + wc * 64 + (lane & 15);
  if (!isV) {
#pragma unroll
    for (int mf = 0; mf < 4; ++mf)
#pragma unroll
      for (int q = 0; q < 4; ++q) {
        unsigned short* cp = &Kb[(row0 + mf * 16 + q) * N + col0];
#pragma unroll
        for (int nf = 0; nf < 4; ++nf) cp[nf * 16] = f2bf(acc[mf][nf][q]);
      }
  } else {
#pragma unroll
    for (int mf = 0; mf < 4; ++mf)
#pragma unroll
      for (int q = 0; q < 4; ++q) {
        const int c = (int)(row0 + mf * 16 + q);
#pragma unroll
        for (int nf = 0; nf < 4; ++nf) {
          const int dcol = (int)(col0 + nf * 16);
          const size_t off = (size_t)(dcol >> 6) * 16384 +
                             (size_t)((c >> 5) * 4 + ((dcol >> 4) & 3)) * 512 +
                             (size_t)(((c >> 3) & 3) * 16 + (dcol & 15)) * 8 +
                             (size_t)(c & 7);
          Vg[off] = f2bf(acc[mf][nf][q]);
        }
      }
  }
}

// ---------------- 256x256 big GEMM, r9 4-phase schedule (proven 78us) ----------------
template <int OUTMODE>
__global__ __launch_bounds__(512, 2) void gemm256(const unsigned short* __restrict__ A,
                                                  const unsigned short* __restrict__ B,
                                                  void* __restrict__ Cout,
                                                  int M, int N, int K, int nbx) {
  __shared__ unsigned short As[2][256 * 64];
  __shared__ unsigned short Bs[2][256 * 64];
  const int tid  = threadIdx.x;
  const int lane = tid & 63;
  const int wid  = tid >> 6;
  const int wr = wid >> 2;
  const int wc = wid & 3;
  const int lo = lane & 15, hi4 = lane >> 4, lo7 = lane & 7;

  const int nwg = gridDim.x;
  const int cpx = nwg >> 3;
  int flat = blockIdx.x;
  flat = (flat & 7) * cpx + (flat >> 3);
  const int bx = flat % nbx;
  const int by = flat / nbx;

  const long arow0 = (long)by * 256;
  const long brow0 = (long)bx * 256;
  const int nt = K >> 6;
  const int nj = nt >> 1;

  auto stageA = [&](int buf, int t) {
#pragma unroll
    for (int li = 0; li < 4; ++li) {
      int gi = li * 512 + tid;
      int row = gi >> 3;
      int cg = (gi & 7) ^ (row & 7);
      __builtin_amdgcn_global_load_lds(
          (const AS1 unsigned int*)&A[(arow0 + row) * K + (t << 6) + cg * 8],
          (AS3 unsigned int*)&As[buf][gi * 8], 16, 0, 0);
    }
  };
  auto stageB = [&](int buf, int t) {
#pragma unroll
    for (int li = 0; li < 4; ++li) {
      int gi = li * 512 + tid;
      int row = gi >> 3;
      int cg = (gi & 7) ^ (row & 7);
      __builtin_amdgcn_global_load_lds(
          (const AS1 unsigned int*)&B[(brow0 + row) * K + (t << 6) + cg * 8],
          (AS3 unsigned int*)&Bs[buf][gi * 8], 16, 0, 0);
    }
  };

  f32x4 acc[8][4];
#pragma unroll
  for (int i = 0; i < 8; ++i)
#pragma unroll
    for (int j = 0; j < 4; ++j) acc[i][j] = (f32x4){0.f, 0.f, 0.f, 0.f};

  stageA(0, 0);
  stageB(0, 0);
  stageB(1, 1);

  for (int j = 0; j < nj; ++j) {
    const int p = 2 * j;
    const bool more = (j + 1 < nj);
    short8 b[4][2];

    asm volatile("s_waitcnt vmcnt(4)" ::: "memory");
    __builtin_amdgcn_sched_barrier(0);
    __builtin_amdgcn_s_barrier();
    {
      short8 a[4][2];
#pragma unroll
      for (int nf = 0; nf < 4; ++nf)
#pragma unroll
        for (int kk = 0; kk < 2; ++kk) {
          const int row = wc * 64 + nf * 16 + lo;
          b[nf][kk] = *(const short8*)&Bs[0][row * 64 + ((kk * 4 + hi4) ^ lo7) * 8];
        }
#pragma unroll
      for (int mf = 0; mf < 4; ++mf)
#pragma unroll
        for (int kk = 0; kk < 2; ++kk) {
          const int row = wr * 128 + mf * 16 + lo;
          a[mf][kk] = *(const short8*)&As[0][row * 64 + ((kk * 4 + hi4) ^ lo7) * 8];
        }
      stageA(1, p + 1);
      __builtin_amdgcn_s_barrier();
      asm volatile("s_waitcnt lgkmcnt(0)" ::: "memory");
      __builtin_amdgcn_s_setprio(1);
#pragma unroll
      for (int kk = 0; kk < 2; ++kk)
#pragma unroll
        for (int mf = 0; mf < 4; ++mf)
#pragma unroll
          for (int nf = 0; nf < 4; ++nf)
            acc[mf][nf] = __builtin_amdgcn_mfma_f32_16x16x32_bf16(a[mf][kk], b[nf][kk], acc[mf][nf], 0, 0, 0);
      __builtin_amdgcn_s_setprio(0);
    }
    {
      short8 a[4][2];
#pragma unroll
      for (int mf = 0; mf < 4; ++mf)
#pragma unroll
        for (int kk = 0; kk < 2; ++kk) {
          const int row = wr * 128 + (mf + 4) * 16 + lo;
          a[mf][kk] = *(const short8*)&As[0][row * 64 + ((kk * 4 + hi4) ^ lo7) * 8];
        }
      if (more) stageB(0, p + 2);
      __builtin_amdgcn_s_barrier();
      asm volatile("s_waitcnt lgkmcnt(0)" ::: "memory");
      __builtin_amdgcn_s_setprio(1);
#pragma unroll
      for (int kk = 0; kk < 2; ++kk)
#pragma unroll
        for (int mf = 0; mf < 4; ++mf)
#pragma unroll
          for (int nf = 0; nf < 4; ++nf)
            acc[mf + 4][nf] = __builtin_amdgcn_mfma_f32_16x16x32_bf16(a[mf][kk], b[nf][kk], acc[mf + 4][nf], 0, 0, 0);
      __builtin_amdgcn_s_setprio(0);
    }
    if (more) asm volatile("s_waitcnt vmcnt(4)" ::: "memory");
    else      asm volatile("s_waitcnt vmcnt(0)" ::: "memory");
    __builtin_amdgcn_sched_barrier(0);
    __builtin_amdgcn_s_barrier();
    {
      short8 a[4][2];
#pragma unroll
      for (int nf = 0; nf < 4; ++nf)
#pragma unroll
        for (int kk = 0; kk < 2; ++kk) {
          const int row = wc * 64 + nf * 16 + lo;
          b[nf][kk] = *(const short8*)&Bs[1][row * 64 + ((kk * 4 + hi4) ^ lo7) * 8];
        }
#pragma unroll
      for (int mf = 0; mf < 4; ++mf)
#pragma unroll
        for (int kk = 0; kk < 2; ++kk) {
          const int row = wr * 128 + mf * 16 + lo;
          a[mf][kk] = *(const short8*)&As[1][row * 64 + ((kk * 4 + hi4) ^ lo7) * 8];
        }
      if (more) stageA(0, p + 2);
      __builtin_amdgcn_s_barrier();
      asm volatile("s_waitcnt lgkmcnt(0)" ::: "memory");
      __builtin_amdgcn_s_setprio(1);
#pragma unroll
      for (int kk = 0; kk < 2; ++kk)
#pragma unroll
        for (int mf = 0; mf < 4; ++mf)
#pragma unroll
          for (int nf = 0; nf < 4; ++nf)
            acc[mf][nf] = __builtin_amdgcn_mfma_f32_16x16x32_bf16(a[mf][kk], b[nf][kk], acc[mf][nf], 0, 0, 0);
      __builtin_amdgcn_s_setprio(0);
    }
    {
      short8 a[4][2];
#pragma unroll
      for (int mf = 0; mf < 4; ++mf)
#pragma unroll
        for (int kk = 0; kk < 2; ++kk) {
          const int row = wr * 128 + (mf + 4) * 16 + lo;
          a[mf][kk] = *(const short8*)&As[1][row * 64 + ((kk * 4 + hi4) ^ lo7) * 8];
        }
      if (more) stageB(1, p + 3);
      __builtin_amdgcn_s_barrier();
      asm volatile("s_waitcnt lgkmcnt(0)" ::: "memory");
      __builtin_amdgcn_s_setprio(1);
#pragma unroll
      for (int kk = 0; kk < 2; ++kk)
#pragma unroll
        for (int mf = 0; mf < 4; ++mf)
#pragma unroll
          for (int nf = 0; nf < 4; ++nf)
            acc[mf + 4][nf] = __builtin_amdgcn_mfma_f32_16x16x32_bf16(a[mf][kk], b[nf][kk], acc[mf + 4][nf], 0, 0, 0);
      __builtin_amdgcn_s_setprio(0);
    }
  }

  const long row0 = (long)by * 256 + wr * 128 + (hi4 << 2);
  const long col0 = (long)bx * 256 + wc * 64 + lo;
  if (OUTMODE == 1) {
    float* C = (float*)Cout;
#pragma unroll
    for (int mf = 0; mf < 8; ++mf)
#pragma unroll
      for (int q = 0; q < 4; ++q) {
        float* cp = &C[(row0 + mf * 16 + q) * N + col0];
#pragma unroll
        for (int nf = 0; nf < 4; ++nf) cp[nf * 16] = acc[mf][nf][q];
      }
  } else {
    unsigned short* C = (unsigned short*)Cout;
#pragma unroll
    for (int mf = 0; mf < 8; ++mf)
#pragma unroll
      for (int q = 0; q < 4; ++q) {
        unsigned short* cp = &C[(row0 + mf * 16 + q) * N + col0];
#pragma unroll
        for (int nf = 0; nf < 4; ++nf) cp[nf * 16] = f2bf(acc[mf][nf][q]);
      }
  }
}

// ---------------- fused attention: register-streamed P (no P-LDS, no mid barrier) ----------------
// sigma-permuted K-fragment rows make the P->PV redistribution a pure lane^32 swap:
// sigma(i) = (i&4)*2 + ((i&8)>>1) + (i&3); lane (lo,hi4) then holds, per cf-pair kk,
// P[q=lo][c-offsets], and after one shfl_xor(32) of packed-bf16 pairs owns the exact
// PV A-fragment PA[kk][j] = P[lo][kk*32 + hi4*8 + j]. LDS = 32KB K only; s[16] never
// materialized (per-kk streaming). V fragments direct from L2 (Vg layout).
__global__ __launch_bounds__(256) void attn_kernel(const unsigned short* __restrict__ Q,
                                                   const unsigned short* __restrict__ Kc,
                                                   const unsigned short* __restrict__ Vg,
                                                   unsigned short* __restrict__ AO) {
  __shared__ unsigned short SH[256 * 64];  // K[c][d], granule-swizzled (32KB)
  const int tid = threadIdx.x, lane = tid & 63, wid = tid >> 6;
  const int lo = lane & 15, hi4 = lane >> 4;
  const int h = blockIdx.y;
  const int n0 = blockIdx.x * 64;

  // stage K_h [c=256][d=64], 16B granule (8/row) swizzled g' = g ^ (c&7)
#pragma unroll
  for (int p = 0; p < 8; ++p) {
    int gi = p * 256 + tid;
    int c  = gi >> 3;
    int gp = gi & 7;
    const unsigned short* src = &Kc[(size_t)c * DIM + h * HD + ((gp ^ (c & 7)) << 3)];
    __builtin_amdgcn_global_load_lds((const AS1 unsigned int*)src,
                                     (AS3 unsigned int*)&SH[gi * 8], 16, 0, 0);
  }

  // Q fragments (wave owns 16 query rows; MFMA B operand, cols = q)
  const int qrow = n0 + wid * 16 + lo;
  const int kc = hi4 * 8;
  short8 aq0 = *(const short8*)&Q[(size_t)qrow * DIM + h * HD + kc];
  short8 aq1 = *(const short8*)&Q[(size_t)qrow * DIM + h * HD + 32 + kc];

  asm volatile("s_waitcnt vmcnt(0)" ::: "memory");
  __builtin_amdgcn_sched_barrier(0);
  __builtin_amdgcn_s_barrier();
  __builtin_amdgcn_sched_barrier(0);

  // sigma(lo) = ((lo>>2)&1)*8 + ((lo>>3)&1)*4 + (lo&3); row = cf*16 + sigma
  const int sig = ((lo >> 2) & 1) * 8 + ((lo >> 3) & 1) * 4 + (lo & 3);
  const int g0  = hi4 ^ (sig & 7);          // swizzled slot, k-chunk hi4
  const bool lowg = (hi4 < 2);

  const unsigned short* vb = &Vg[(size_t)h * 16384 + (size_t)lane * 8];
  const float cexp = 0.125f * 1.44269504088896f;  // SCALE * log2(e)
  float rs = 0.f;
  f32x4 o[4];
#pragma unroll
  for (int nf = 0; nf < 4; ++nf) o[nf] = (f32x4){0.f, 0.f, 0.f, 0.f};

#pragma unroll
  for (int kk = 0; kk < 8; ++kk) {
    // QK^T for cf0 = 2kk, cf1 = 2kk+1 (sigma-permuted A rows)
    const int r0 = kk * 32 + sig;
    short8 b0 = *(const short8*)&SH[r0 * 64 + g0 * 8];
    short8 b1 = *(const short8*)&SH[r0 * 64 + (g0 ^ 4) * 8];
    f32x4 z0 = (f32x4){0.f, 0.f, 0.f, 0.f};
    z0 = __builtin_amdgcn_mfma_f32_16x16x32_bf16(b0, aq0, z0, 0, 0, 0);
    z0 = __builtin_amdgcn_mfma_f32_16x16x32_bf16(b1, aq1, z0, 0, 0, 0);
    const int r1 = r0 + 16;
    short8 c0 = *(const short8*)&SH[r1 * 64 + g0 * 8];
    short8 c1 = *(const short8*)&SH[r1 * 64 + (g0 ^ 4) * 8];
    f32x4 z1 = (f32x4){0.f, 0.f, 0.f, 0.f};
    z1 = __builtin_amdgcn_mfma_f32_16x16x32_bf16(c0, aq0, z1, 0, 0, 0);
    z1 = __builtin_amdgcn_mfma_f32_16x16x32_bf16(c1, aq1, z1, 0, 0, 0);

    // exp (raw v_exp_f32; args bounded) + running row-sum
#pragma unroll
    for (int q = 0; q < 4; ++q) {
      z0[q] = __builtin_amdgcn_exp2f(z0[q] * cexp);
      z1[q] = __builtin_amdgcn_exp2f(z1[q] * cexp);
      rs += z0[q] + z1[q];
    }

    // pack to bf16 pairs
    unsigned int k0 = cvtpk_bf16(z0[0], z0[1]), k1 = cvtpk_bf16(z0[2], z0[3]);
    unsigned int m0 = cvtpk_bf16(z1[0], z1[1]), m1 = cvtpk_bf16(z1[2], z1[3]);

    // lane^32 exchange: lanes hi4<2 offer cf1 words, hi4>=2 offer cf0 words
    unsigned int of0 = lowg ? m0 : k0;
    unsigned int of1 = lowg ? m1 : k1;
    unsigned int rv0 = __shfl_xor(of0, 32, 64);
    unsigned int rv1 = __shfl_xor(of1, 32, 64);
    unsigned int kp0 = lowg ? k0 : m0;   // kept pair
    unsigned int kp1 = lowg ? k1 : m1;

    union { uint4 u; short8 s; } pa;
    pa.u.x = lowg ? kp0 : rv0;
    pa.u.y = lowg ? kp1 : rv1;
    pa.u.z = lowg ? rv0 : kp0;
    pa.u.w = lowg ? rv1 : kp1;

    // PV for this 32-c chunk: B = V fragments direct from global (L2-hot)
#pragma unroll
    for (int nf = 0; nf < 4; ++nf) {
      short8 bv = *(const short8*)&vb[(size_t)(kk * 4 + nf) * 512];
      o[nf] = __builtin_amdgcn_mfma_f32_16x16x32_bf16(pa.s, bv, o[nf], 0, 0, 0);
    }
  }

  // complete the row-sums (union over the 4 hi4 lanes of each q-row)
  rs += __shfl_xor(rs, 16, 64);
  rs += __shfl_xor(rs, 32, 64);
  const float rinv = __builtin_amdgcn_rcpf(rs);

  // epilogue: per-row denominators via intra-wave shfl; deferred normalization
  float rq[4];
#pragma unroll
  for (int q = 0; q < 4; ++q) rq[q] = __shfl(rinv, (hi4 << 2) + q, 64);
  const size_t orow0 = n0 + wid * 16 + (hi4 << 2);
  const int ocol = h * HD + lo;
#pragma unroll
  for (int nf = 0; nf < 4; ++nf) {
    unsigned int u0 = cvtpk_bf16(o[nf][0] * rq[0], o[nf][1] * rq[1]);
    unsigned int u1 = cvtpk_bf16(o[nf][2] * rq[2], o[nf][3] * rq[3]);
    AO[(orow0 + 0) * DIM + ocol + nf * 16] = (unsigned short)u0;
    AO[(orow0 + 1) * DIM + ocol + nf * 16] = (unsigned short)(u0 >> 16);
    AO[(orow0 + 2) * DIM + ocol + nf * 16] = (unsigned short)u1;
    AO[(orow0 + 3) * DIM + ocol + nf * 16] = (unsigned short)(u1 >> 16);
  }
}

extern "C" void kernel_launch(void* const* d_in, const int* in_sizes, int n_in,
                              void* d_out, int out_size, void* d_ws, size_t ws_size,
                              hipStream_t stream) {
  (void)in_sizes; (void)n_in; (void)out_size; (void)ws_size;
  const float* x    = (const float*)d_in[0];
  const float* kv   = (const float*)d_in[1];
  // d_in[2] = rope_bias, d_in[7] = Wrope: bias constant over softmax axis -> unused.
  const float* Wq   = (const float*)d_in[3];
  const float* Wk   = (const float*)d_in[4];
  const float* Wv   = (const float*)d_in[5];
  const float* Wout = (const float*)d_in[6];
  float* out = (float*)d_out;

  char* ws = (char*)d_ws;
  unsigned short* xb  = (unsigned short*)(ws);                 // 64 MB
  unsigned short* Qb  = (unsigned short*)(ws + 67108864);      // 64 MB (reused as attn_out)
  unsigned short* wqb = (unsigned short*)(ws + 134217728);     // 2 MB each
  unsigned short* wkb = (unsigned short*)(ws + 136314880);
  unsigned short* wvb = (unsigned short*)(ws + 138412032);
  unsigned short* wob = (unsigned short*)(ws + 140509184);
  unsigned short* kvb = (unsigned short*)(ws + 142606336);     // 0.5 MB
  unsigned short* Kb  = (unsigned short*)(ws + 143130624);     // 0.5 MB (K row-major)
  unsigned short* Vgb = (unsigned short*)(ws + 144179200);     // 0.5 MB (V fragment layout)

  cvt_all<<<2624, 256, 0, stream>>>(x, Wq, Wk, Wv, Wout, kv,
                                    xb, wqb, wkb, wvb, wob, kvb);

  kvproj<<<dim3(8, 2, 2), 256, 0, stream>>>(kvb, wkb, wvb, Kb, Vgb);

  gemm256<0><<<512, 512, 0, stream>>>(xb, wqb, Qb, N_TOK, DIM, DIM, DIM / 256);

  attn_kernel<<<dim3(N_TOK / 64, NH), 256, 0, stream>>>(Qb, Kb, Vgb, Qb);

  gemm256<1><<<512, 512, 0, stream>>>(Qb, wob, out, N_TOK, DIM, DIM, DIM / 256);
}